// Round 12
// baseline (932.119 us; speedup 1.0000x reference)
//
#include <hip/hip_runtime.h>
#include <hip/hip_bf16.h>

#define N_NODES 32768
#define F_IN    32
#define HC      64
#define HEADS   4
#define NE      524288
#define NET     (NE + N_NODES)   /* 557056 = 2176*256 */
#define NG      64
#define TT      512
#define OUTF    24

__device__ __forceinline__ float lrelu(float x){ return x > 0.f ? x : 0.2f*x; }
__device__ __forceinline__ float eluf (float x){ return x > 0.f ? x : __expf(x)-1.f; }
__device__ __forceinline__ float sigmf(float x){ return 1.f/(1.f+__expf(-x)); }
__device__ __forceinline__ float tanhfast(float x){ return 1.f - 2.f/(__expf(2.f*x)+1.f); }

// ---------------- CSR build: incoming-edge lists per destination ----------------
__global__ __launch_bounds__(256) void k_deg(const int* __restrict__ ei,
                                             int* __restrict__ deg){
  int e = blockIdx.x*256 + threadIdx.x;   // e < NET
  int d = (e < NE) ? ei[NE+e] : (e - NE);
  atomicAdd(deg + d, 1);
}

// exclusive prefix sum of deg[32768] -> rowptr[32769]; single block of 1024
__global__ __launch_bounds__(1024) void k_scan(const int* __restrict__ deg,
                                               int* __restrict__ rowptr){
  __shared__ int ps[1024];
  const int t = threadIdx.x;
  const int base = t*32;
  int local[32]; int s = 0;
  #pragma unroll
  for(int i=0;i<32;i++){ local[i]=deg[base+i]; s+=local[i]; }
  ps[t]=s; __syncthreads();
  for(int off=1; off<1024; off<<=1){
    int v = (t>=off) ? ps[t-off] : 0;
    __syncthreads();
    ps[t]+=v;
    __syncthreads();
  }
  int run = (t==0) ? 0 : ps[t-1];
  #pragma unroll
  for(int i=0;i<32;i++){ rowptr[base+i]=run; run+=local[i]; }
  if(t==1023) rowptr[N_NODES]=run;
}

__global__ __launch_bounds__(256) void k_fill(const int* __restrict__ ei,
                                              const int* __restrict__ rowptr,
                                              int* __restrict__ cur,
                                              int* __restrict__ col){
  int e = blockIdx.x*256 + threadIdx.x;   // e < NET
  int s, d;
  if(e < NE){ s = ei[e]; d = ei[NE+e]; } else { s = e-NE; d = s; }
  int pos = atomicAdd(cur + d, 1);
  col[rowptr[d] + pos] = s;
}

// ---------------- GAT layer 1: h1 = x @ W1   [N,32]@[32,256] ----------------
__global__ __launch_bounds__(256) void k_gemm1(const float* __restrict__ x,
                                               const float* __restrict__ W1,
                                               float* __restrict__ h1){
  __shared__ __align__(16) float xs[64*32];
  __shared__ __align__(16) float ws[32*256];
  const int tid = threadIdx.x;
  const int row0 = blockIdx.x*64;
  const float4* xg = (const float4*)(x + row0*F_IN);
  float4* xs4 = (float4*)xs;
  for(int i=tid;i<512;i+=256) xs4[i]=xg[i];
  const float4* wg=(const float4*)W1; float4* ws4=(float4*)ws;
  for(int i=tid;i<2048;i+=256) ws4[i]=wg[i];
  __syncthreads();
  float wc[32];
  #pragma unroll
  for(int k=0;k<32;k++) wc[k]=ws[k*256+tid];
  for(int r=0;r<64;r++){
    const float4* xr=(const float4*)(xs + r*32);
    float acc=0.f;
    #pragma unroll
    for(int k4=0;k4<8;k4++){
      float4 v=xr[k4];
      acc += v.x*wc[4*k4]+v.y*wc[4*k4+1]+v.z*wc[4*k4+2]+v.w*wc[4*k4+3];
    }
    h1[(row0+r)*256+tid]=acc;
  }
}

__global__ __launch_bounds__(256) void k_alpha1(const float* __restrict__ h1,
                                                const float* __restrict__ a_src,
                                                const float* __restrict__ a_dst,
                                                float* __restrict__ as1,
                                                float* __restrict__ ad1){
  int t = blockIdx.x*256 + threadIdx.x;   // t < N*4
  int n = t>>2, h = t&3;
  const float4* hp=(const float4*)(h1 + n*256 + h*64);
  const float4* ap=(const float4*)(a_src + h*64);
  const float4* dp=(const float4*)(a_dst + h*64);
  float sa=0.f, sd=0.f;
  #pragma unroll
  for(int i=0;i<16;i++){
    float4 v=hp[i], a=ap[i], d=dp[i];
    sa += v.x*a.x+v.y*a.y+v.z*a.z+v.w*a.w;
    sd += v.x*d.x+v.y*d.y+v.z*d.z+v.w*d.w;
  }
  as1[t]=sa; ad1[t]=sd;
}

// fused gather: softmax (no max-subtract; logits O(5)) + aggregate + bias + ELU.
// one wave per node; lane covers one float4 of 256 output channels; head = lane>>4.
__global__ __launch_bounds__(256) void k_gat1(const int* __restrict__ rowptr,
                                              const int* __restrict__ col,
                                              const float* __restrict__ as1,
                                              const float* __restrict__ ad1,
                                              const float* __restrict__ h1,
                                              const float* __restrict__ b1,
                                              float* __restrict__ out1){
  const int node = blockIdx.x*4 + (threadIdx.x>>6);
  const int lane = threadIdx.x & 63;
  const int h    = lane>>4;
  const int beg = rowptr[node], end = rowptr[node+1];
  const float ad = ad1[node*4+h];
  float4 acc = make_float4(0.f,0.f,0.f,0.f);
  float s = 0.f;
  int j = beg;
  for(; j+1 < end; j += 2){
    int s0 = col[j], s1 = col[j+1];
    float w0 = __expf(lrelu(as1[s0*4+h] + ad));
    float w1 = __expf(lrelu(as1[s1*4+h] + ad));
    float4 v0 = *(const float4*)(h1 + s0*256 + lane*4);
    float4 v1 = *(const float4*)(h1 + s1*256 + lane*4);
    acc.x += w0*v0.x + w1*v1.x;
    acc.y += w0*v0.y + w1*v1.y;
    acc.z += w0*v0.z + w1*v1.z;
    acc.w += w0*v0.w + w1*v1.w;
    s += w0 + w1;
  }
  if(j < end){
    int s0 = col[j];
    float w0 = __expf(lrelu(as1[s0*4+h] + ad));
    float4 v0 = *(const float4*)(h1 + s0*256 + lane*4);
    acc.x += w0*v0.x; acc.y += w0*v0.y; acc.z += w0*v0.z; acc.w += w0*v0.w;
    s += w0;
  }
  const float inv = 1.f/(s + 1e-16f);
  float4 bb = ((const float4*)b1)[lane];
  float4 o;
  o.x = eluf(acc.x*inv + bb.x);
  o.y = eluf(acc.y*inv + bb.y);
  o.z = eluf(acc.z*inv + bb.z);
  o.w = eluf(acc.w*inv + bb.w);
  ((float4*)(out1 + node*256))[lane] = o;
}

// ---------------- GAT layer 2: h2 = out1 @ W2   [N,256]@[256,64] ----------------
__global__ __launch_bounds__(256) void k_gemm2(const float* __restrict__ in,
                                               const float* __restrict__ W2,
                                               float* __restrict__ h2){
  __shared__ __align__(16) float xs[64*256];
  const int tid=threadIdx.x;
  const int row0=blockIdx.x*64;
  const float4* xg=(const float4*)(in + row0*256);
  float4* xs4=(float4*)xs;
  for(int i=tid;i<4096;i+=256) xs4[i]=xg[i];
  __syncthreads();
  const int c0=(tid&15)*4;
  const int r0=(tid>>4)*4;
  float acc[4][4]={};
  for(int k=0;k<256;k+=4){
    float wv[4][4];
    #pragma unroll
    for(int i=0;i<4;i++){
      float4 w=*(const float4*)(W2+(k+i)*64+c0);
      wv[i][0]=w.x; wv[i][1]=w.y; wv[i][2]=w.z; wv[i][3]=w.w;
    }
    #pragma unroll
    for(int i=0;i<4;i++){
      float4 xv=*(const float4*)(xs+(r0+i)*256+k);
      #pragma unroll
      for(int j=0;j<4;j++)
        acc[i][j]+=xv.x*wv[0][j]+xv.y*wv[1][j]+xv.z*wv[2][j]+xv.w*wv[3][j];
    }
  }
  #pragma unroll
  for(int i=0;i<4;i++)
    *(float4*)(h2+(row0+r0+i)*64+c0)=make_float4(acc[i][0],acc[i][1],acc[i][2],acc[i][3]);
}

__global__ __launch_bounds__(256) void k_alpha2(const float* __restrict__ h2,
                                                const float* __restrict__ a_src,
                                                const float* __restrict__ a_dst,
                                                float* __restrict__ as2,
                                                float* __restrict__ ad2){
  int n = blockIdx.x*256 + threadIdx.x;   // n < N
  const float4* hp=(const float4*)(h2+n*64);
  float sa=0.f, sd=0.f;
  #pragma unroll
  for(int i=0;i<16;i++){
    float4 v=hp[i];
    float4 a=((const float4*)a_src)[i];
    float4 d=((const float4*)a_dst)[i];
    sa+=v.x*a.x+v.y*a.y+v.z*a.z+v.w*a.w;
    sd+=v.x*d.x+v.y*d.y+v.z*d.z+v.w*d.w;
  }
  as2[n]=sa; ad2[n]=sd;
}

// fused gather layer 2: one wave per node, lane = channel (64 channels)
__global__ __launch_bounds__(256) void k_gat2(const int* __restrict__ rowptr,
                                              const int* __restrict__ col,
                                              const float* __restrict__ as2,
                                              const float* __restrict__ ad2,
                                              const float* __restrict__ h2,
                                              const float* __restrict__ b2,
                                              float* __restrict__ out2){
  const int node = blockIdx.x*4 + (threadIdx.x>>6);
  const int lane = threadIdx.x & 63;
  const int beg = rowptr[node], end = rowptr[node+1];
  const float ad = ad2[node];
  float acc = 0.f, s = 0.f;
  int j = beg;
  for(; j+1 < end; j += 2){
    int s0 = col[j], s1 = col[j+1];
    float w0 = __expf(lrelu(as2[s0] + ad));
    float w1 = __expf(lrelu(as2[s1] + ad));
    acc += w0*h2[s0*64+lane] + w1*h2[s1*64+lane];
    s += w0 + w1;
  }
  if(j < end){
    int s0 = col[j];
    float w0 = __expf(lrelu(as2[s0] + ad));
    acc += w0*h2[s0*64+lane];
    s += w0;
  }
  const float inv = 1.f/(s + 1e-16f);
  out2[node*64+lane] = eluf(acc*inv + b2[lane]);
}

// ---------------- GRU: gi1 = in @ Wih0^T + bih0   [N,64]@[64,192] ----------------
__global__ __launch_bounds__(256) void k_gemm_gi(const float* __restrict__ in,
                                                 const float* __restrict__ Wih,
                                                 const float* __restrict__ bih,
                                                 float* __restrict__ gi){
  __shared__ __align__(16) float xs[64*64];
  __shared__ float wT[64*192];
  const int tid=threadIdx.x;
  const int row0=blockIdx.x*64;
  const float4* xg=(const float4*)(in+row0*64);
  float4* xs4=(float4*)xs;
  for(int i=tid;i<1024;i+=256) xs4[i]=xg[i];
  for(int i=tid;i<12288;i+=256){ wT[(i&63)*192+(i>>6)] = Wih[i]; }
  __syncthreads();
  if(tid<192){
    float wr[64];
    #pragma unroll
    for(int k=0;k<64;k++) wr[k]=wT[k*192+tid];
    const float bj=bih[tid];
    for(int r=0;r<64;r++){
      float acc=bj;
      const float4* xr=(const float4*)(xs+r*64);
      #pragma unroll
      for(int k4=0;k4<16;k4++){
        float4 v=xr[k4];
        acc+=v.x*wr[4*k4]+v.y*wr[4*k4+1]+v.z*wr[4*k4+2]+v.w*wr[4*k4+3];
      }
      gi[(row0+r)*192+tid]=acc;
    }
  }
}

// Fused 2-layer GRU, 320 threads (5 waves), 1 block/graph, 2 rows per thread.
// r11 post-mortem: weights WERE resident (VGPR=76) but LDS instruction
// throughput is the wall: 9 waves x 16 ds_read_b128 = 144 instr x ~12cyc =
// 1728 cyc/step. Fix: each h-read amortizes over TWO dot products.
//   threads   0-191: gh1 row t (Whh0) AND gi2 row t (Wih1) — both read h1s,
//                    both legally consume h1^(i) (verified skew, r10/r11).
//   threads 192-287: gh2 rows 2u, 2u+1 (Whh1) — read h2s.
//   threads 288-319: staging only (matvec computed on clamped rows, not stored).
// LDS reads/step: 5 waves x 16 = 80 b128 (~960 cyc) — 1.8x less than r11.
// Weights via r2-proven transposed-LDS staging (conflict-free, overwritten
// backing store -> loads not sinkable). gi1 chunked as r9 (no in-loop vmcnt).
__global__ __launch_bounds__(320) void k_gruH(const float* __restrict__ gi1,
                                              const float* __restrict__ Whh0,
                                              const float* __restrict__ bhh0,
                                              const float* __restrict__ Wih1,
                                              const float* __restrict__ bih1,
                                              const float* __restrict__ Whh1,
                                              const float* __restrict__ bhh1,
                                              const float* __restrict__ Wl,
                                              const float* __restrict__ bl,
                                              float* __restrict__ fout){
  __shared__ __align__(16) float h1s[64];
  __shared__ __align__(16) float h2s[64];
  __shared__ float gh1s[192];
  __shared__ float gi2s[192];
  __shared__ float gh2s[192];
  __shared__ __align__(16) float gic[64*192];   // 48 KB: weight staging, then gi1 chunks
  const int tid  = threadIdx.x;
  const int lane = tid & 63;
  const int w    = tid >> 6;
  const int b    = blockIdx.x;
  const float* gib = gi1 + (size_t)b*TT*192;
  float4* gic4 = (float4*)gic;

  const bool cA  = (tid < 192);
  const int  u0  = tid - 192;
  const int  u   = (!cA && u0 < 96) ? u0 : 95;       // clamp staging-only threads
  const bool act = cA || (u0 < 96);
  const int rowA = cA ? tid : 2*u;
  const int rowB = cA ? tid : 2*u+1;
  const float* hsrc = cA ? h1s : h2s;

  // ---- stage W^T in LDS (conflict-free reads), load two rows into regs ----
  float wA[64], wB[64];
  for(int i=tid;i<12288;i+=320) gic[(i&63)*192+(i>>6)] = Whh0[i];
  __syncthreads();
  if(cA){
    #pragma unroll
    for(int k=0;k<64;k++) wA[k] = gic[k*192+rowA];
  }
  __syncthreads();
  for(int i=tid;i<12288;i+=320) gic[(i&63)*192+(i>>6)] = Wih1[i];
  __syncthreads();
  if(cA){
    #pragma unroll
    for(int k=0;k<64;k++) wB[k] = gic[k*192+rowA];
  }
  __syncthreads();
  for(int i=tid;i<12288;i+=320) gic[(i&63)*192+(i>>6)] = Whh1[i];
  __syncthreads();
  if(!cA){
    #pragma unroll
    for(int k=0;k<64;k++){ wA[k] = gic[k*192+rowA]; wB[k] = gic[k*192+rowB]; }
  }
  __syncthreads();
  const float bA = cA ? bhh0[rowA] : bhh1[rowA];
  const float bB = cA ? bih1[rowA] : bhh1[rowB];

  if(tid < 64){ h1s[tid]=0.f; h2s[tid]=0.f; }
  __syncthreads();

#define MATVEC() do{ \
    float a0=bA, a1=0.f, a2=0.f, a3=0.f; \
    float c0=bB, c1=0.f, c2=0.f, c3=0.f; \
    const float4* h4p = (const float4*)hsrc; \
    _Pragma("unroll") \
    for(int k4=0;k4<16;k4++){ \
      float4 h4 = h4p[k4]; \
      a0 = fmaf(h4.x, wA[4*k4  ], a0);  c0 = fmaf(h4.x, wB[4*k4  ], c0); \
      a1 = fmaf(h4.y, wA[4*k4+1], a1);  c1 = fmaf(h4.y, wB[4*k4+1], c1); \
      a2 = fmaf(h4.z, wA[4*k4+2], a2);  c2 = fmaf(h4.z, wB[4*k4+2], c2); \
      a3 = fmaf(h4.w, wA[4*k4+3], a3);  c3 = fmaf(h4.w, wB[4*k4+3], c3); \
    } \
    if(act){ \
      if(cA){ gh1s[rowA] = (a0+a1)+(a2+a3); gi2s[rowA] = (c0+c1)+(c2+c3); } \
      else  { gh2s[rowA] = (a0+a1)+(a2+a3); gh2s[rowB] = (c0+c1)+(c2+c3); } \
    } \
  }while(0)

  for(int c=0;c<8;c++){
    // stage gi1 steps [c*64, c*64+64) -> LDS (coalesced float4 burst, one drain)
    const float4* g4 = (const float4*)gib + (size_t)c*3072;
    for(int l=tid; l<3072; l+=320) gic4[l] = g4[l];
    __syncthreads();
    for(int j=0;j<64;j++){
      const int i = c*64 + j;
      MATVEC();
      __syncthreads();
      // ---- phase B: gate updates ----
      if(w == 0){
        float r = sigmf(gic[j*192+lane]     + gh1s[lane]);
        float z = sigmf(gic[j*192+64+lane]  + gh1s[64+lane]);
        float n = tanhfast(gic[j*192+128+lane] + r*gh1s[128+lane]);
        h1s[lane] = (1.f-z)*n + z*h1s[lane];
      } else if(w == 3){
        if(i >= 1){
          float r = sigmf(gi2s[lane]     + gh2s[lane]);
          float z = sigmf(gi2s[64+lane]  + gh2s[64+lane]);
          float n = tanhfast(gi2s[128+lane] + r*gh2s[128+lane]);
          h2s[lane] = (1.f-z)*n + z*h2s[lane];
        }
      }
      __syncthreads();
    }
  }
  // epilogue: produce gi2/gh2 for step 511; final h2 update
  MATVEC();
  __syncthreads();
  if(w == 3){
    float r = sigmf(gi2s[lane]     + gh2s[lane]);
    float z = sigmf(gi2s[64+lane]  + gh2s[64+lane]);
    float n = tanhfast(gi2s[128+lane] + r*gh2s[128+lane]);
    h2s[lane] = (1.f-z)*n + z*h2s[lane];
  }
  __syncthreads();
#undef MATVEC

  if(tid < 24){
    float acc = bl[tid];
    const float4* wl4 = (const float4*)(Wl + tid*64);
    #pragma unroll
    for(int k4=0;k4<16;k4++){
      float4 h4 = *(const float4*)(h2s + 4*k4);
      float4 w4 = wl4[k4];
      acc += h4.x*w4.x + h4.y*w4.y + h4.z*w4.z + h4.w*w4.w;
    }
    fout[b*24+tid] = acc;
  }
}

extern "C" void kernel_launch(void* const* d_in, const int* in_sizes, int n_in,
                              void* d_out, int out_size, void* d_ws, size_t ws_size,
                              hipStream_t stream){
  const float* x     =(const float*)d_in[0];
  const int*   ei    =(const int*  )d_in[1];
  const float* W1    =(const float*)d_in[3];
  const float* a_src1=(const float*)d_in[4];
  const float* a_dst1=(const float*)d_in[5];
  const float* b1    =(const float*)d_in[6];
  const float* W2    =(const float*)d_in[7];
  const float* a_src2=(const float*)d_in[8];
  const float* a_dst2=(const float*)d_in[9];
  const float* b2    =(const float*)d_in[10];
  const float* Wih0  =(const float*)d_in[11];
  const float* Whh0  =(const float*)d_in[12];
  const float* bih0  =(const float*)d_in[13];
  const float* bhh0  =(const float*)d_in[14];
  const float* Wih1  =(const float*)d_in[15];
  const float* Whh1  =(const float*)d_in[16];
  const float* bih1  =(const float*)d_in[17];
  const float* bhh1  =(const float*)d_in[18];
  const float* Wl    =(const float*)d_in[19];
  const float* bl    =(const float*)d_in[20];

  float* ws   = (float*)d_ws;
  float* h1   = ws;                  // 8388608 (dead after k_gat1)
  float* gi   = ws;                  // alias: written by k_gemm_gi after h1 is dead
  float* out1 = ws + 8388608;        // 8388608
  float* out2 = out1;                // alias (out1 dead after k_gemm2)
  float* h2   = ws + 16777216;       // 2097152
  float* as1  = ws + 18874368;       // 131072
  float* ad1  = as1 + 131072;        // 131072
  float* as2  = ad1 + 131072;        // 32768
  float* ad2  = as2 + 32768;         // 32768
  int* rowptr = (int*)(ad2 + 32768); // 32769 (padded to 32800)
  int* deg    = rowptr + 32800;      // 32768
  int* cur    = deg + 32768;         // 32768 (contiguous with deg: one memset)
  int* col    = cur + 32768;         // 557056
  float* fo   = (float*)d_out;

  hipMemsetAsync(deg, 0, 2*32768*sizeof(int), stream);  // deg + cur

  k_deg  <<<2176,256,0,stream>>>(ei,deg);
  k_scan <<<1  ,1024,0,stream>>>(deg,rowptr);
  k_fill <<<2176,256,0,stream>>>(ei,rowptr,cur,col);

  k_gemm1 <<<512 ,256,0,stream>>>(x,W1,h1);
  k_alpha1<<<512 ,256,0,stream>>>(h1,a_src1,a_dst1,as1,ad1);
  k_gat1  <<<8192,256,0,stream>>>(rowptr,col,as1,ad1,h1,b1,out1);
  k_gemm2 <<<512 ,256,0,stream>>>(out1,W2,h2);
  k_alpha2<<<128 ,256,0,stream>>>(h2,a_src2,a_dst2,as2,ad2);
  k_gat2  <<<8192,256,0,stream>>>(rowptr,col,as2,ad2,h2,b2,out2);
  k_gemm_gi<<<512,256,0,stream>>>(out2,Wih0,bih0,gi);
  k_gruH  <<<64 ,320,0,stream>>>(gi,Whh0,bhh0,Wih1,bih1,Whh1,bhh1,Wl,bl,fo);
  (void)in_sizes; (void)n_in; (void)out_size; (void)ws_size;
}

// Round 13
// 779.925 us; speedup vs baseline: 1.1951x; 1.1951x over previous
//
#include <hip/hip_runtime.h>
#include <hip/hip_bf16.h>

#define N_NODES 32768
#define F_IN    32
#define HC      64
#define HEADS   4
#define NE      524288
#define NET     (NE + N_NODES)   /* 557056 = 2176*256 */
#define NG      64
#define TT      512
#define OUTF    24

__device__ __forceinline__ float lrelu(float x){ return x > 0.f ? x : 0.2f*x; }
__device__ __forceinline__ float eluf (float x){ return x > 0.f ? x : __expf(x)-1.f; }
__device__ __forceinline__ float sigmf(float x){ return 1.f/(1.f+__expf(-x)); }
__device__ __forceinline__ float tanhfast(float x){ return 1.f - 2.f/(__expf(2.f*x)+1.f); }
__device__ __forceinline__ float bcast(float v, int k){
  return __int_as_float(__builtin_amdgcn_readlane(__float_as_int(v), k));
}

// ---------------- CSR build: incoming-edge lists per destination ----------------
__global__ __launch_bounds__(256) void k_deg(const int* __restrict__ ei,
                                             int* __restrict__ deg){
  int e = blockIdx.x*256 + threadIdx.x;   // e < NET
  int d = (e < NE) ? ei[NE+e] : (e - NE);
  atomicAdd(deg + d, 1);
}

__global__ __launch_bounds__(1024) void k_scan(const int* __restrict__ deg,
                                               int* __restrict__ rowptr){
  __shared__ int ps[1024];
  const int t = threadIdx.x;
  const int base = t*32;
  int local[32]; int s = 0;
  #pragma unroll
  for(int i=0;i<32;i++){ local[i]=deg[base+i]; s+=local[i]; }
  ps[t]=s; __syncthreads();
  for(int off=1; off<1024; off<<=1){
    int v = (t>=off) ? ps[t-off] : 0;
    __syncthreads();
    ps[t]+=v;
    __syncthreads();
  }
  int run = (t==0) ? 0 : ps[t-1];
  #pragma unroll
  for(int i=0;i<32;i++){ rowptr[base+i]=run; run+=local[i]; }
  if(t==1023) rowptr[N_NODES]=run;
}

__global__ __launch_bounds__(256) void k_fill(const int* __restrict__ ei,
                                              const int* __restrict__ rowptr,
                                              int* __restrict__ cur,
                                              int* __restrict__ col){
  int e = blockIdx.x*256 + threadIdx.x;   // e < NET
  int s, d;
  if(e < NE){ s = ei[e]; d = ei[NE+e]; } else { s = e-NE; d = s; }
  int pos = atomicAdd(cur + d, 1);
  col[rowptr[d] + pos] = s;
}

// ---------------- GAT layer 1, restructured (h1 never materialized) ----------------
// p[k,h] projectors: as1[n,h] = x[n,:] . (W1[:, h*64:h*64+64] @ a_src[h,:])
__global__ __launch_bounds__(256) void k_prep(const float* __restrict__ W1,
                                              const float* __restrict__ a_src,
                                              const float* __restrict__ a_dst,
                                              float* __restrict__ p){
  const int t = threadIdx.x;          // 256 = 32 k x (4 h x 2 src/dst)
  const int k = t>>3, q = t&7;
  const int h = q>>1, isd = q&1;
  const float* av = (isd ? a_dst : a_src) + h*64;
  const float* wr = W1 + k*256 + h*64;
  float acc = 0.f;
  #pragma unroll
  for(int c=0;c<64;c++) acc += wr[c]*av[c];
  p[(isd?128:0) + k*4 + h] = acc;
}

// as1/ad1 directly from x: [N,32]@[32,4] twice
__global__ __launch_bounds__(256) void k_alpha1x(const float* __restrict__ x,
                                                 const float* __restrict__ p,
                                                 float* __restrict__ as1,
                                                 float* __restrict__ ad1){
  __shared__ float ps[256];
  const int tid = threadIdx.x;
  ps[tid] = p[tid];
  __syncthreads();
  const int n = blockIdx.x*256 + tid;
  const float4* xr = (const float4*)(x + n*32);
  float sa0=0.f,sa1=0.f,sa2=0.f,sa3=0.f, sd0=0.f,sd1=0.f,sd2=0.f,sd3=0.f;
  #pragma unroll
  for(int k4=0;k4<8;k4++){
    float4 v = xr[k4];
    const float* pa = ps + (4*k4)*4;
    const float* pd = ps + 128 + (4*k4)*4;
    sa0 += v.x*pa[0] + v.y*pa[4] + v.z*pa[8]  + v.w*pa[12];
    sa1 += v.x*pa[1] + v.y*pa[5] + v.z*pa[9]  + v.w*pa[13];
    sa2 += v.x*pa[2] + v.y*pa[6] + v.z*pa[10] + v.w*pa[14];
    sa3 += v.x*pa[3] + v.y*pa[7] + v.z*pa[11] + v.w*pa[15];
    sd0 += v.x*pd[0] + v.y*pd[4] + v.z*pd[8]  + v.w*pd[12];
    sd1 += v.x*pd[1] + v.y*pd[5] + v.z*pd[9]  + v.w*pd[13];
    sd2 += v.x*pd[2] + v.y*pd[6] + v.z*pd[10] + v.w*pd[14];
    sd3 += v.x*pd[3] + v.y*pd[7] + v.z*pd[11] + v.w*pd[15];
  }
  *(float4*)(as1+n*4) = make_float4(sa0,sa1,sa2,sa3);
  *(float4*)(ad1+n*4) = make_float4(sd0,sd1,sd2,sd3);
}

// aggregate x per (node, head): agg[d,h,k] = sum_e w_e^h x[src_e,k]; s14 = sum w.
// Linear algebra identity: sum_e w_e h1[src] = (sum_e w_e x[src]) @ W1 — so the
// gather reads 128 B/edge (x row) instead of 1 KB/edge (h1 row). One wave/node;
// lane: c = lane&31 channel, handles heads {lane>>5, 2+(lane>>5)}.
__global__ __launch_bounds__(256) void k_gatx(const int* __restrict__ rowptr,
                                              const int* __restrict__ col,
                                              const float* __restrict__ as1,
                                              const float* __restrict__ ad1,
                                              const float* __restrict__ x,
                                              float* __restrict__ agg,
                                              float* __restrict__ s14){
  const int node = blockIdx.x*4 + (threadIdx.x>>6);
  const int lane = threadIdx.x & 63;
  const int h0   = lane>>5;                  // 0 or 1
  const int c    = lane & 31;
  const int beg = rowptr[node], end = rowptr[node+1];
  const float adA = ad1[node*4 + h0];
  const float adB = ad1[node*4 + h0 + 2];
  float accA=0.f, accB=0.f, wsA=0.f, wsB=0.f;
  int j = beg;
  for(; j+1 < end; j += 2){
    int s0 = col[j], s1 = col[j+1];
    float4 q0 = *(const float4*)(as1 + s0*4);
    float4 q1 = *(const float4*)(as1 + s1*4);
    float aA0 = h0 ? q0.y : q0.x, aB0 = h0 ? q0.w : q0.z;
    float aA1 = h0 ? q1.y : q1.x, aB1 = h0 ? q1.w : q1.z;
    float wA0 = __expf(lrelu(aA0 + adA));
    float wB0 = __expf(lrelu(aB0 + adB));
    float wA1 = __expf(lrelu(aA1 + adA));
    float wB1 = __expf(lrelu(aB1 + adB));
    float x0 = x[s0*32 + c];
    float x1 = x[s1*32 + c];
    accA += wA0*x0 + wA1*x1;
    accB += wB0*x0 + wB1*x1;
    wsA  += wA0 + wA1;
    wsB  += wB0 + wB1;
  }
  if(j < end){
    int s0 = col[j];
    float4 q0 = *(const float4*)(as1 + s0*4);
    float aA0 = h0 ? q0.y : q0.x, aB0 = h0 ? q0.w : q0.z;
    float wA0 = __expf(lrelu(aA0 + adA));
    float wB0 = __expf(lrelu(aB0 + adB));
    float x0 = x[s0*32 + c];
    accA += wA0*x0; accB += wB0*x0;
    wsA += wA0; wsB += wB0;
  }
  agg[node*128 + h0*32 + c]     = accA;
  agg[node*128 + (h0+2)*32 + c] = accB;
  if(c == 0){
    s14[node*4 + h0]     = wsA;
    s14[node*4 + h0 + 2] = wsB;
  }
}

// epilogue GEMM: out1[n, h*64+cc] = ELU( (agg[n,h,:].W1[:,h*64+cc]) / s + b1 )
__global__ __launch_bounds__(256) void k_gemm1e(const float* __restrict__ agg,
                                                const float* __restrict__ W1,
                                                const float* __restrict__ s14,
                                                const float* __restrict__ b1,
                                                float* __restrict__ out1){
  __shared__ __align__(16) float ags[64*128];   // 32 KB
  __shared__ __align__(16) float wsh[32*256];   // 32 KB
  __shared__ float sv[64*4];
  const int tid = threadIdx.x;
  const int row0 = blockIdx.x*64;
  const float4* ag = (const float4*)(agg + row0*128);
  float4* ags4 = (float4*)ags;
  for(int i=tid;i<2048;i+=256) ags4[i]=ag[i];
  const float4* wg=(const float4*)W1; float4* ws4=(float4*)wsh;
  for(int i=tid;i<2048;i+=256) ws4[i]=wg[i];
  const float4* sg=(const float4*)(s14 + row0*4);
  float4* sv4=(float4*)sv;
  if(tid<64) sv4[tid]=sg[tid];
  __syncthreads();
  const int h = tid>>6;
  float wc[32];
  #pragma unroll
  for(int k=0;k<32;k++) wc[k]=wsh[k*256 + tid];   // column tid, conflict-free
  const float bb = b1[tid];
  for(int r=0;r<64;r++){
    const float4* ar=(const float4*)(ags + r*128 + h*32);
    float acc=0.f;
    #pragma unroll
    for(int k4=0;k4<8;k4++){
      float4 v=ar[k4];
      acc += v.x*wc[4*k4]+v.y*wc[4*k4+1]+v.z*wc[4*k4+2]+v.w*wc[4*k4+3];
    }
    float inv = 1.f/(sv[r*4+h] + 1e-16f);
    out1[(row0+r)*256 + tid] = eluf(acc*inv + bb);
  }
}

// ---------------- GAT layer 2: h2 = out1 @ W2   [N,256]@[256,64] ----------------
__global__ __launch_bounds__(256) void k_gemm2(const float* __restrict__ in,
                                               const float* __restrict__ W2,
                                               float* __restrict__ h2){
  __shared__ __align__(16) float xs[64*256];
  const int tid=threadIdx.x;
  const int row0=blockIdx.x*64;
  const float4* xg=(const float4*)(in + row0*256);
  float4* xs4=(float4*)xs;
  for(int i=tid;i<4096;i+=256) xs4[i]=xg[i];
  __syncthreads();
  const int c0=(tid&15)*4;
  const int r0=(tid>>4)*4;
  float acc[4][4]={};
  for(int k=0;k<256;k+=4){
    float wv[4][4];
    #pragma unroll
    for(int i=0;i<4;i++){
      float4 w=*(const float4*)(W2+(k+i)*64+c0);
      wv[i][0]=w.x; wv[i][1]=w.y; wv[i][2]=w.z; wv[i][3]=w.w;
    }
    #pragma unroll
    for(int i=0;i<4;i++){
      float4 xv=*(const float4*)(xs+(r0+i)*256+k);
      #pragma unroll
      for(int j=0;j<4;j++)
        acc[i][j]+=xv.x*wv[0][j]+xv.y*wv[1][j]+xv.z*wv[2][j]+xv.w*wv[3][j];
    }
  }
  #pragma unroll
  for(int i=0;i<4;i++)
    *(float4*)(h2+(row0+r0+i)*64+c0)=make_float4(acc[i][0],acc[i][1],acc[i][2],acc[i][3]);
}

__global__ __launch_bounds__(256) void k_alpha2(const float* __restrict__ h2,
                                                const float* __restrict__ a_src,
                                                const float* __restrict__ a_dst,
                                                float* __restrict__ as2,
                                                float* __restrict__ ad2){
  int n = blockIdx.x*256 + threadIdx.x;   // n < N
  const float4* hp=(const float4*)(h2+n*64);
  float sa=0.f, sd=0.f;
  #pragma unroll
  for(int i=0;i<16;i++){
    float4 v=hp[i];
    float4 a=((const float4*)a_src)[i];
    float4 d=((const float4*)a_dst)[i];
    sa+=v.x*a.x+v.y*a.y+v.z*a.z+v.w*a.w;
    sd+=v.x*d.x+v.y*d.y+v.z*d.z+v.w*d.w;
  }
  as2[n]=sa; ad2[n]=sd;
}

// fused gather layer 2: one wave per node, lane = channel (64 channels)
__global__ __launch_bounds__(256) void k_gat2(const int* __restrict__ rowptr,
                                              const int* __restrict__ col,
                                              const float* __restrict__ as2,
                                              const float* __restrict__ ad2,
                                              const float* __restrict__ h2,
                                              const float* __restrict__ b2,
                                              float* __restrict__ out2){
  const int node = blockIdx.x*4 + (threadIdx.x>>6);
  const int lane = threadIdx.x & 63;
  const int beg = rowptr[node], end = rowptr[node+1];
  const float ad = ad2[node];
  float acc = 0.f, s = 0.f;
  int j = beg;
  for(; j+1 < end; j += 2){
    int s0 = col[j], s1 = col[j+1];
    float w0 = __expf(lrelu(as2[s0] + ad));
    float w1 = __expf(lrelu(as2[s1] + ad));
    acc += w0*h2[s0*64+lane] + w1*h2[s1*64+lane];
    s += w0 + w1;
  }
  if(j < end){
    int s0 = col[j];
    float w0 = __expf(lrelu(as2[s0] + ad));
    acc += w0*h2[s0*64+lane];
    s += w0;
  }
  const float inv = 1.f/(s + 1e-16f);
  out2[node*64+lane] = eluf(acc*inv + b2[lane]);
}

// ---------------- GRU: gi1 = in @ Wih0^T + bih0   [N,64]@[64,192] ----------------
__global__ __launch_bounds__(256) void k_gemm_gi(const float* __restrict__ in,
                                                 const float* __restrict__ Wih,
                                                 const float* __restrict__ bih,
                                                 float* __restrict__ gi){
  __shared__ __align__(16) float xs[64*64];
  __shared__ float wT[64*192];
  const int tid=threadIdx.x;
  const int row0=blockIdx.x*64;
  const float4* xg=(const float4*)(in+row0*64);
  float4* xs4=(float4*)xs;
  for(int i=tid;i<1024;i+=256) xs4[i]=xg[i];
  for(int i=tid;i<12288;i+=256){ wT[(i&63)*192+(i>>6)] = Wih[i]; }
  __syncthreads();
  if(tid<192){
    float wr[64];
    #pragma unroll
    for(int k=0;k<64;k++) wr[k]=wT[k*192+tid];
    const float bj=bih[tid];
    for(int r=0;r<64;r++){
      float acc=bj;
      const float4* xr=(const float4*)(xs+r*64);
      #pragma unroll
      for(int k4=0;k4<16;k4++){
        float4 v=xr[k4];
        acc+=v.x*wr[4*k4]+v.y*wr[4*k4+1]+v.z*wr[4*k4+2]+v.w*wr[4*k4+3];
      }
      gi[(row0+r)*192+tid]=acc;
    }
  }
}

// Fused 2-layer GRU — r8's k_gruR VERBATIM (best measured: 443us).
__global__ __launch_bounds__(576,3) void k_gruR(const float* __restrict__ gi1,
                                                const float* __restrict__ Whh0,
                                                const float* __restrict__ bhh0,
                                                const float* __restrict__ Wih1,
                                                const float* __restrict__ bih1,
                                                const float* __restrict__ Whh1,
                                                const float* __restrict__ bhh1,
                                                const float* __restrict__ Wl,
                                                const float* __restrict__ bl,
                                                float* __restrict__ fout){
  __shared__ float h1s[64];
  __shared__ float h2s[64];
  __shared__ float gh1s[192];
  __shared__ float gi2s[192];
  __shared__ float gh2s[192];
  __shared__ float g1r[2][192];   // gi1 ring (parity)
  const int tid  = threadIdx.x;
  const int w    = tid >> 6;
  const int lane = tid & 63;
  const int b    = blockIdx.x;
  const float* gib = gi1 + (size_t)b*TT*192;

  const int crew = w/3;                     // wave-uniform
  const int row  = (w%3)*64 + lane;
  const float* W  = (crew==0) ? Whh0 : (crew==1) ? Wih1 : Whh1;
  const float* bb = (crew==0) ? bhh0 : (crew==1) ? bih1 : bhh1;
  float* dst      = (crew==0) ? gh1s : (crew==1) ? gi2s : gh2s;

  const float4* wp = (const float4*)(W + row*64);
  float4 Wv0=wp[0],  Wv1=wp[1],  Wv2=wp[2],  Wv3=wp[3];
  float4 Wv4=wp[4],  Wv5=wp[5],  Wv6=wp[6],  Wv7=wp[7];
  float4 Wv8=wp[8],  Wv9=wp[9],  WvA=wp[10], WvB=wp[11];
  float4 WvC=wp[12], WvD=wp[13], WvE=wp[14], WvF=wp[15];
  const float bias = bb[row];

  float giv = 0.f;
  if(w < 3){                                // crew0: prefill ring step 0, reg step 1
    g1r[0][row] = gib[row];
    giv = gib[192 + row];
  }
  if(tid < 64){ h1s[tid]=0.f; h2s[tid]=0.f; }
  __syncthreads();

  for(int i=0;i<=TT;i++){
    // ---- phase A ----
    float hv = (crew==2) ? h2s[lane] : h1s[lane];
    if(w < 3){
      int pst = i+1;
      if(pst < TT) g1r[pst&1][row] = giv;   // value loaded last iter (latency hidden)
      int nst = i+2;
      if(nst < TT) giv = gib[nst*192 + row];
    }
    float a0=bias, a1=0.f, a2=0.f, a3=0.f;
#define DOT4(WV, BASE) \
    a0 = fmaf(bcast(hv, BASE+0), WV.x, a0); \
    a1 = fmaf(bcast(hv, BASE+1), WV.y, a1); \
    a2 = fmaf(bcast(hv, BASE+2), WV.z, a2); \
    a3 = fmaf(bcast(hv, BASE+3), WV.w, a3);
    DOT4(Wv0, 0)  DOT4(Wv1, 4)  DOT4(Wv2, 8)  DOT4(Wv3, 12)
    DOT4(Wv4, 16) DOT4(Wv5, 20) DOT4(Wv6, 24) DOT4(Wv7, 28)
    DOT4(Wv8, 32) DOT4(Wv9, 36) DOT4(WvA, 40) DOT4(WvB, 44)
    DOT4(WvC, 48) DOT4(WvD, 52) DOT4(WvE, 56) DOT4(WvF, 60)
#undef DOT4
    dst[row] = (a0+a1)+(a2+a3);
    __syncthreads();
    // ---- phase B: gate updates (guards define the skew) ----
    if(w == 0){
      if(i < TT){
        float r = sigmf(g1r[i&1][lane]     + gh1s[lane]);
        float z = sigmf(g1r[i&1][64+lane]  + gh1s[64+lane]);
        float n = tanhfast(g1r[i&1][128+lane] + r*gh1s[128+lane]);
        h1s[lane] = (1.f-z)*n + z*h1s[lane];
      }
    } else if(w == 3){
      if(i >= 1){
        float r = sigmf(gi2s[lane]     + gh2s[lane]);
        float z = sigmf(gi2s[64+lane]  + gh2s[64+lane]);
        float n = tanhfast(gi2s[128+lane] + r*gh2s[128+lane]);
        h2s[lane] = (1.f-z)*n + z*h2s[lane];
      }
    }
    __syncthreads();
  }

  if(tid < 24){
    float acc = bl[tid];
    const float4* wl4 = (const float4*)(Wl + tid*64);
    #pragma unroll
    for(int k4=0;k4<16;k4++){
      float4 h4 = *(const float4*)(h2s + 4*k4);
      float4 w4 = wl4[k4];
      acc += h4.x*w4.x + h4.y*w4.y + h4.z*w4.z + h4.w*w4.w;
    }
    fout[b*24+tid] = acc;
  }
}

extern "C" void kernel_launch(void* const* d_in, const int* in_sizes, int n_in,
                              void* d_out, int out_size, void* d_ws, size_t ws_size,
                              hipStream_t stream){
  const float* x     =(const float*)d_in[0];
  const int*   ei    =(const int*  )d_in[1];
  const float* W1    =(const float*)d_in[3];
  const float* a_src1=(const float*)d_in[4];
  const float* a_dst1=(const float*)d_in[5];
  const float* b1    =(const float*)d_in[6];
  const float* W2    =(const float*)d_in[7];
  const float* a_src2=(const float*)d_in[8];
  const float* a_dst2=(const float*)d_in[9];
  const float* b2    =(const float*)d_in[10];
  const float* Wih0  =(const float*)d_in[11];
  const float* Whh0  =(const float*)d_in[12];
  const float* bih0  =(const float*)d_in[13];
  const float* bhh0  =(const float*)d_in[14];
  const float* Wih1  =(const float*)d_in[15];
  const float* Whh1  =(const float*)d_in[16];
  const float* bih1  =(const float*)d_in[17];
  const float* bhh1  =(const float*)d_in[18];
  const float* Wl    =(const float*)d_in[19];
  const float* bl    =(const float*)d_in[20];

  float* ws   = (float*)d_ws;
  float* agg  = ws;                  // 4194304 [N,128] (dead after k_gemm1e)
  float* s14  = ws + 4194304;        // 131072 [N,4]
  float* gi   = ws;                  // overwrites agg after it's dead
  float* out1 = ws + 8388608;        // 8388608
  float* out2 = out1;                // alias (out1 dead after k_gemm2)
  float* h2   = ws + 16777216;       // 2097152
  float* as1  = ws + 18874368;       // 131072
  float* ad1  = as1 + 131072;        // 131072
  float* as2  = ad1 + 131072;        // 32768
  float* ad2  = as2 + 32768;         // 32768
  float* pbuf = ad2 + 32768;         // 256 (padded 512)
  int* rowptr = (int*)(pbuf + 512);  // 32769 (padded to 32800)
  int* deg    = rowptr + 32800;      // 32768
  int* cur    = deg + 32768;         // 32768 (contiguous with deg: one memset)
  int* col    = cur + 32768;         // 557056
  float* fo   = (float*)d_out;

  hipMemsetAsync(deg, 0, 2*32768*sizeof(int), stream);  // deg + cur

  k_deg   <<<2176,256,0,stream>>>(ei,deg);
  k_scan  <<<1  ,1024,0,stream>>>(deg,rowptr);
  k_fill  <<<2176,256,0,stream>>>(ei,rowptr,cur,col);

  k_prep   <<<1   ,256,0,stream>>>(W1,a_src1,a_dst1,pbuf);
  k_alpha1x<<<128 ,256,0,stream>>>(x,pbuf,as1,ad1);
  k_gatx   <<<8192,256,0,stream>>>(rowptr,col,as1,ad1,x,agg,s14);
  k_gemm1e <<<512 ,256,0,stream>>>(agg,W1,s14,b1,out1);
  k_gemm2  <<<512 ,256,0,stream>>>(out1,W2,h2);
  k_alpha2 <<<128 ,256,0,stream>>>(h2,a_src2,a_dst2,as2,ad2);
  k_gat2   <<<8192,256,0,stream>>>(rowptr,col,as2,ad2,h2,b2,out2);
  k_gemm_gi<<<512 ,256,0,stream>>>(out2,Wih0,bih0,gi);
  k_gruR   <<<64  ,576,0,stream>>>(gi,Whh0,bhh0,Wih1,bih1,Whh1,bhh1,Wl,bl,fo);
  (void)in_sizes; (void)n_in; (void)out_size; (void)ws_size;
}

// Round 14
// 755.774 us; speedup vs baseline: 1.2333x; 1.0320x over previous
//
#include <hip/hip_runtime.h>
#include <hip/hip_bf16.h>

#define N_NODES 32768
#define F_IN    32
#define HC      64
#define HEADS   4
#define NE      524288
#define NET     (NE + N_NODES)   /* 557056 = 2176*256 */
#define NG      64
#define TT      512
#define OUTF    24

__device__ __forceinline__ float lrelu(float x){ return x > 0.f ? x : 0.2f*x; }
__device__ __forceinline__ float eluf (float x){ return x > 0.f ? x : __expf(x)-1.f; }
__device__ __forceinline__ float sigmf(float x){ return 1.f/(1.f+__expf(-x)); }
__device__ __forceinline__ float tanhfast(float x){ return 1.f - 2.f/(__expf(2.f*x)+1.f); }
__device__ __forceinline__ float bcast(float v, int k){
  return __int_as_float(__builtin_amdgcn_readlane(__float_as_int(v), k));
}

// ---------------- CSR build: incoming-edge lists per destination ----------------
__global__ __launch_bounds__(256) void k_deg(const int* __restrict__ ei,
                                             int* __restrict__ deg){
  int e = blockIdx.x*256 + threadIdx.x;   // e < NET
  int d = (e < NE) ? ei[NE+e] : (e - NE);
  atomicAdd(deg + d, 1);
}

__global__ __launch_bounds__(1024) void k_scan(const int* __restrict__ deg,
                                               int* __restrict__ rowptr){
  __shared__ int ps[1024];
  const int t = threadIdx.x;
  const int base = t*32;
  int local[32]; int s = 0;
  #pragma unroll
  for(int i=0;i<32;i++){ local[i]=deg[base+i]; s+=local[i]; }
  ps[t]=s; __syncthreads();
  for(int off=1; off<1024; off<<=1){
    int v = (t>=off) ? ps[t-off] : 0;
    __syncthreads();
    ps[t]+=v;
    __syncthreads();
  }
  int run = (t==0) ? 0 : ps[t-1];
  #pragma unroll
  for(int i=0;i<32;i++){ rowptr[base+i]=run; run+=local[i]; }
  if(t==1023) rowptr[N_NODES]=run;
}

__global__ __launch_bounds__(256) void k_fill(const int* __restrict__ ei,
                                              const int* __restrict__ rowptr,
                                              int* __restrict__ cur,
                                              int* __restrict__ col){
  int e = blockIdx.x*256 + threadIdx.x;   // e < NET
  int s, d;
  if(e < NE){ s = ei[e]; d = ei[NE+e]; } else { s = e-NE; d = s; }
  int pos = atomicAdd(cur + d, 1);
  col[rowptr[d] + pos] = s;
}

// ---------------- GAT layer 1, restructured (h1 never materialized) ----------------
// alpha projectors computed in-block (redundant per block, trivially cheap), then
// as1/ad1 directly from x: [N,32]@[32,4] twice.
__global__ __launch_bounds__(256) void k_alpha1x(const float* __restrict__ x,
                                                 const float* __restrict__ W1,
                                                 const float* __restrict__ a_src,
                                                 const float* __restrict__ a_dst,
                                                 float* __restrict__ as1,
                                                 float* __restrict__ ad1){
  __shared__ float ps[256];
  const int tid = threadIdx.x;
  {
    const int k = tid>>3, q = tid&7;
    const int h = q>>1, isd = q&1;
    const float* av = (isd ? a_dst : a_src) + h*64;
    const float* wr = W1 + k*256 + h*64;
    float acc = 0.f;
    #pragma unroll
    for(int c=0;c<64;c++) acc += wr[c]*av[c];
    ps[(isd?128:0) + k*4 + h] = acc;
  }
  __syncthreads();
  const int n = blockIdx.x*256 + tid;
  const float4* xr = (const float4*)(x + n*32);
  float sa0=0.f,sa1=0.f,sa2=0.f,sa3=0.f, sd0=0.f,sd1=0.f,sd2=0.f,sd3=0.f;
  #pragma unroll
  for(int k4=0;k4<8;k4++){
    float4 v = xr[k4];
    const float* pa = ps + (4*k4)*4;
    const float* pd = ps + 128 + (4*k4)*4;
    sa0 += v.x*pa[0] + v.y*pa[4] + v.z*pa[8]  + v.w*pa[12];
    sa1 += v.x*pa[1] + v.y*pa[5] + v.z*pa[9]  + v.w*pa[13];
    sa2 += v.x*pa[2] + v.y*pa[6] + v.z*pa[10] + v.w*pa[14];
    sa3 += v.x*pa[3] + v.y*pa[7] + v.z*pa[11] + v.w*pa[15];
    sd0 += v.x*pd[0] + v.y*pd[4] + v.z*pd[8]  + v.w*pd[12];
    sd1 += v.x*pd[1] + v.y*pd[5] + v.z*pd[9]  + v.w*pd[13];
    sd2 += v.x*pd[2] + v.y*pd[6] + v.z*pd[10] + v.w*pd[14];
    sd3 += v.x*pd[3] + v.y*pd[7] + v.z*pd[11] + v.w*pd[15];
  }
  *(float4*)(as1+n*4) = make_float4(sa0,sa1,sa2,sa3);
  *(float4*)(ad1+n*4) = make_float4(sd0,sd1,sd2,sd3);
}

// aggregate x per (node, head): agg[d,h,k] = sum_e w_e^h x[src_e,k]; s14 = sum w.
// 4-wide unrolled edge loop: 8+ independent loads in flight per iteration.
__global__ __launch_bounds__(256) void k_gatx(const int* __restrict__ rowptr,
                                              const int* __restrict__ col,
                                              const float* __restrict__ as1,
                                              const float* __restrict__ ad1,
                                              const float* __restrict__ x,
                                              float* __restrict__ agg,
                                              float* __restrict__ s14){
  const int node = blockIdx.x*4 + (threadIdx.x>>6);
  const int lane = threadIdx.x & 63;
  const int h0   = lane>>5;                  // 0 or 1
  const int c    = lane & 31;
  const int beg = rowptr[node], end = rowptr[node+1];
  const float adA = ad1[node*4 + h0];
  const float adB = ad1[node*4 + h0 + 2];
  float accA=0.f, accB=0.f, wsA=0.f, wsB=0.f;
  int j = beg;
  for(; j+3 < end; j += 4){
    int s0 = col[j], s1 = col[j+1], s2 = col[j+2], s3 = col[j+3];
    float4 q0 = *(const float4*)(as1 + s0*4);
    float4 q1 = *(const float4*)(as1 + s1*4);
    float4 q2 = *(const float4*)(as1 + s2*4);
    float4 q3 = *(const float4*)(as1 + s3*4);
    float x0 = x[s0*32 + c];
    float x1 = x[s1*32 + c];
    float x2 = x[s2*32 + c];
    float x3 = x[s3*32 + c];
    float wA0 = __expf(lrelu((h0?q0.y:q0.x) + adA));
    float wA1 = __expf(lrelu((h0?q1.y:q1.x) + adA));
    float wA2 = __expf(lrelu((h0?q2.y:q2.x) + adA));
    float wA3 = __expf(lrelu((h0?q3.y:q3.x) + adA));
    float wB0 = __expf(lrelu((h0?q0.w:q0.z) + adB));
    float wB1 = __expf(lrelu((h0?q1.w:q1.z) + adB));
    float wB2 = __expf(lrelu((h0?q2.w:q2.z) + adB));
    float wB3 = __expf(lrelu((h0?q3.w:q3.z) + adB));
    accA += wA0*x0 + wA1*x1 + wA2*x2 + wA3*x3;
    accB += wB0*x0 + wB1*x1 + wB2*x2 + wB3*x3;
    wsA  += (wA0+wA1) + (wA2+wA3);
    wsB  += (wB0+wB1) + (wB2+wB3);
  }
  for(; j < end; j++){
    int s0 = col[j];
    float4 q0 = *(const float4*)(as1 + s0*4);
    float wA0 = __expf(lrelu((h0?q0.y:q0.x) + adA));
    float wB0 = __expf(lrelu((h0?q0.w:q0.z) + adB));
    float x0 = x[s0*32 + c];
    accA += wA0*x0; accB += wB0*x0;
    wsA += wA0; wsB += wB0;
  }
  agg[node*128 + h0*32 + c]     = accA;
  agg[node*128 + (h0+2)*32 + c] = accB;
  if(c == 0){
    s14[node*4 + h0]     = wsA;
    s14[node*4 + h0 + 2] = wsB;
  }
}

// Fused: out1 = ELU(agg@W1/s + b1) [LDS only] ; h2 = out1@W2 ; as2/ad2 from h2.
// 32-row tiles: ags 16KB (reused as h2 tile) + o1s 32KB + sv -> ~48.5KB LDS,
// 2 blocks/CU. Saves out1's 33MB HBM write + 33MB read + alpha2's 8MB read
// and two kernel launches vs r13.
__global__ __launch_bounds__(256) void k_g12(const float* __restrict__ agg,
                                             const float* __restrict__ W1,
                                             const float* __restrict__ s14,
                                             const float* __restrict__ b1,
                                             const float* __restrict__ W2,
                                             const float* __restrict__ a_src2,
                                             const float* __restrict__ a_dst2,
                                             float* __restrict__ h2,
                                             float* __restrict__ as2,
                                             float* __restrict__ ad2){
  __shared__ __align__(16) float ags[32*128];   // 16KB; reused as h2 tile (8KB)
  __shared__ __align__(16) float o1s[32*256];   // 32KB
  __shared__ float sv[128];
  const int tid  = threadIdx.x;
  const int row0 = blockIdx.x*32;
  const float4* ag = (const float4*)(agg + (size_t)row0*128);
  float4* a4 = (float4*)ags;
  for(int i=tid;i<1024;i+=256) a4[i]=ag[i];
  if(tid<32) ((float4*)sv)[tid]=((const float4*)(s14+row0*4))[tid];
  float wc[32];
  #pragma unroll
  for(int k=0;k<32;k++) wc[k]=W1[k*256+tid];    // column tid, coalesced across lanes
  const float bb=b1[tid];
  __syncthreads();
  // phase 1: out1 tile (normalized + bias + ELU) into LDS
  const int h = tid>>6;
  for(int r=0;r<32;r++){
    const float4* ar=(const float4*)(ags + r*128 + h*32);
    float acc=0.f;
    #pragma unroll
    for(int k4=0;k4<8;k4++){
      float4 v=ar[k4];
      acc += v.x*wc[4*k4]+v.y*wc[4*k4+1]+v.z*wc[4*k4+2]+v.w*wc[4*k4+3];
    }
    float inv = 1.f/(sv[r*4+h] + 1e-16f);
    o1s[r*256+tid] = eluf(acc*inv + bb);
  }
  __syncthreads();
  // phase 2: h2 tile [32x64] = o1s @ W2
  const int c0=(tid&15)*4;
  const int r0=(tid>>4)*2;
  float acc2[2][4]={};
  for(int k=0;k<256;k+=4){
    float wv[4][4];
    #pragma unroll
    for(int i=0;i<4;i++){
      float4 w=*(const float4*)(W2+(k+i)*64+c0);
      wv[i][0]=w.x; wv[i][1]=w.y; wv[i][2]=w.z; wv[i][3]=w.w;
    }
    #pragma unroll
    for(int i=0;i<2;i++){
      float4 xv=*(const float4*)(o1s+(r0+i)*256+k);
      #pragma unroll
      for(int j=0;j<4;j++)
        acc2[i][j]+=xv.x*wv[0][j]+xv.y*wv[1][j]+xv.z*wv[2][j]+xv.w*wv[3][j];
    }
  }
  float* h2s = ags;   // safe: ags last read before phase-1 barrier
  #pragma unroll
  for(int i=0;i<2;i++){
    float4 o = make_float4(acc2[i][0],acc2[i][1],acc2[i][2],acc2[i][3]);
    *(float4*)(h2 + (size_t)(row0+r0+i)*64 + c0) = o;
    *(float4*)(h2s + (r0+i)*64 + c0) = o;
  }
  __syncthreads();
  // phase 3: alpha2 for these 32 rows
  if(tid < 32){
    const float4* hp=(const float4*)(h2s + tid*64);
    float sa=0.f, sd=0.f;
    #pragma unroll
    for(int i=0;i<16;i++){
      float4 v=hp[i];
      float4 a=((const float4*)a_src2)[i];
      float4 d=((const float4*)a_dst2)[i];
      sa+=v.x*a.x+v.y*a.y+v.z*a.z+v.w*a.w;
      sd+=v.x*d.x+v.y*d.y+v.z*d.z+v.w*d.w;
    }
    as2[row0+tid]=sa; ad2[row0+tid]=sd;
  }
}

// fused gather layer 2: one wave per node, lane = channel; 4-wide unrolled.
__global__ __launch_bounds__(256) void k_gat2(const int* __restrict__ rowptr,
                                              const int* __restrict__ col,
                                              const float* __restrict__ as2,
                                              const float* __restrict__ ad2,
                                              const float* __restrict__ h2,
                                              const float* __restrict__ b2,
                                              float* __restrict__ out2){
  const int node = blockIdx.x*4 + (threadIdx.x>>6);
  const int lane = threadIdx.x & 63;
  const int beg = rowptr[node], end = rowptr[node+1];
  const float ad = ad2[node];
  float acc = 0.f, s = 0.f;
  int j = beg;
  for(; j+3 < end; j += 4){
    int s0 = col[j], s1 = col[j+1], s2 = col[j+2], s3 = col[j+3];
    float a0 = as2[s0], a1 = as2[s1], a2 = as2[s2], a3 = as2[s3];
    float v0 = h2[s0*64+lane], v1 = h2[s1*64+lane];
    float v2 = h2[s2*64+lane], v3 = h2[s3*64+lane];
    float w0 = __expf(lrelu(a0 + ad));
    float w1 = __expf(lrelu(a1 + ad));
    float w2 = __expf(lrelu(a2 + ad));
    float w3 = __expf(lrelu(a3 + ad));
    acc += w0*v0 + w1*v1 + w2*v2 + w3*v3;
    s += (w0+w1) + (w2+w3);
  }
  for(; j < end; j++){
    int s0 = col[j];
    float w0 = __expf(lrelu(as2[s0] + ad));
    acc += w0*h2[s0*64+lane];
    s += w0;
  }
  const float inv = 1.f/(s + 1e-16f);
  out2[node*64+lane] = eluf(acc*inv + b2[lane]);
}

// ---------------- GRU: gi1 = in @ Wih0^T + bih0   [N,64]@[64,192] ----------------
__global__ __launch_bounds__(256) void k_gemm_gi(const float* __restrict__ in,
                                                 const float* __restrict__ Wih,
                                                 const float* __restrict__ bih,
                                                 float* __restrict__ gi){
  __shared__ __align__(16) float xs[64*64];
  __shared__ float wT[64*192];
  const int tid=threadIdx.x;
  const int row0=blockIdx.x*64;
  const float4* xg=(const float4*)(in+row0*64);
  float4* xs4=(float4*)xs;
  for(int i=tid;i<1024;i+=256) xs4[i]=xg[i];
  for(int i=tid;i<12288;i+=256){ wT[(i&63)*192+(i>>6)] = Wih[i]; }
  __syncthreads();
  if(tid<192){
    float wr[64];
    #pragma unroll
    for(int k=0;k<64;k++) wr[k]=wT[k*192+tid];
    const float bj=bih[tid];
    for(int r=0;r<64;r++){
      float acc=bj;
      const float4* xr=(const float4*)(xs+r*64);
      #pragma unroll
      for(int k4=0;k4<16;k4++){
        float4 v=xr[k4];
        acc+=v.x*wr[4*k4]+v.y*wr[4*k4+1]+v.z*wr[4*k4+2]+v.w*wr[4*k4+3];
      }
      gi[(row0+r)*192+tid]=acc;
    }
  }
}

// Fused 2-layer GRU — r8's k_gruR VERBATIM (best measured: 443us).
__global__ __launch_bounds__(576,3) void k_gruR(const float* __restrict__ gi1,
                                                const float* __restrict__ Whh0,
                                                const float* __restrict__ bhh0,
                                                const float* __restrict__ Wih1,
                                                const float* __restrict__ bih1,
                                                const float* __restrict__ Whh1,
                                                const float* __restrict__ bhh1,
                                                const float* __restrict__ Wl,
                                                const float* __restrict__ bl,
                                                float* __restrict__ fout){
  __shared__ float h1s[64];
  __shared__ float h2s[64];
  __shared__ float gh1s[192];
  __shared__ float gi2s[192];
  __shared__ float gh2s[192];
  __shared__ float g1r[2][192];   // gi1 ring (parity)
  const int tid  = threadIdx.x;
  const int w    = tid >> 6;
  const int lane = tid & 63;
  const int b    = blockIdx.x;
  const float* gib = gi1 + (size_t)b*TT*192;

  const int crew = w/3;                     // wave-uniform
  const int row  = (w%3)*64 + lane;
  const float* W  = (crew==0) ? Whh0 : (crew==1) ? Wih1 : Whh1;
  const float* bb = (crew==0) ? bhh0 : (crew==1) ? bih1 : bhh1;
  float* dst      = (crew==0) ? gh1s : (crew==1) ? gi2s : gh2s;

  const float4* wp = (const float4*)(W + row*64);
  float4 Wv0=wp[0],  Wv1=wp[1],  Wv2=wp[2],  Wv3=wp[3];
  float4 Wv4=wp[4],  Wv5=wp[5],  Wv6=wp[6],  Wv7=wp[7];
  float4 Wv8=wp[8],  Wv9=wp[9],  WvA=wp[10], WvB=wp[11];
  float4 WvC=wp[12], WvD=wp[13], WvE=wp[14], WvF=wp[15];
  const float bias = bb[row];

  float giv = 0.f;
  if(w < 3){                                // crew0: prefill ring step 0, reg step 1
    g1r[0][row] = gib[row];
    giv = gib[192 + row];
  }
  if(tid < 64){ h1s[tid]=0.f; h2s[tid]=0.f; }
  __syncthreads();

  for(int i=0;i<=TT;i++){
    // ---- phase A ----
    float hv = (crew==2) ? h2s[lane] : h1s[lane];
    if(w < 3){
      int pst = i+1;
      if(pst < TT) g1r[pst&1][row] = giv;   // value loaded last iter (latency hidden)
      int nst = i+2;
      if(nst < TT) giv = gib[nst*192 + row];
    }
    float a0=bias, a1=0.f, a2=0.f, a3=0.f;
#define DOT4(WV, BASE) \
    a0 = fmaf(bcast(hv, BASE+0), WV.x, a0); \
    a1 = fmaf(bcast(hv, BASE+1), WV.y, a1); \
    a2 = fmaf(bcast(hv, BASE+2), WV.z, a2); \
    a3 = fmaf(bcast(hv, BASE+3), WV.w, a3);
    DOT4(Wv0, 0)  DOT4(Wv1, 4)  DOT4(Wv2, 8)  DOT4(Wv3, 12)
    DOT4(Wv4, 16) DOT4(Wv5, 20) DOT4(Wv6, 24) DOT4(Wv7, 28)
    DOT4(Wv8, 32) DOT4(Wv9, 36) DOT4(WvA, 40) DOT4(WvB, 44)
    DOT4(WvC, 48) DOT4(WvD, 52) DOT4(WvE, 56) DOT4(WvF, 60)
#undef DOT4
    dst[row] = (a0+a1)+(a2+a3);
    __syncthreads();
    // ---- phase B: gate updates (guards define the skew) ----
    if(w == 0){
      if(i < TT){
        float r = sigmf(g1r[i&1][lane]     + gh1s[lane]);
        float z = sigmf(g1r[i&1][64+lane]  + gh1s[64+lane]);
        float n = tanhfast(g1r[i&1][128+lane] + r*gh1s[128+lane]);
        h1s[lane] = (1.f-z)*n + z*h1s[lane];
      }
    } else if(w == 3){
      if(i >= 1){
        float r = sigmf(gi2s[lane]     + gh2s[lane]);
        float z = sigmf(gi2s[64+lane]  + gh2s[64+lane]);
        float n = tanhfast(gi2s[128+lane] + r*gh2s[128+lane]);
        h2s[lane] = (1.f-z)*n + z*h2s[lane];
      }
    }
    __syncthreads();
  }

  if(tid < 24){
    float acc = bl[tid];
    const float4* wl4 = (const float4*)(Wl + tid*64);
    #pragma unroll
    for(int k4=0;k4<16;k4++){
      float4 h4 = *(const float4*)(h2s + 4*k4);
      float4 w4 = wl4[k4];
      acc += h4.x*w4.x + h4.y*w4.y + h4.z*w4.z + h4.w*w4.w;
    }
    fout[b*24+tid] = acc;
  }
}

extern "C" void kernel_launch(void* const* d_in, const int* in_sizes, int n_in,
                              void* d_out, int out_size, void* d_ws, size_t ws_size,
                              hipStream_t stream){
  const float* x     =(const float*)d_in[0];
  const int*   ei    =(const int*  )d_in[1];
  const float* W1    =(const float*)d_in[3];
  const float* a_src1=(const float*)d_in[4];
  const float* a_dst1=(const float*)d_in[5];
  const float* b1    =(const float*)d_in[6];
  const float* W2    =(const float*)d_in[7];
  const float* a_src2=(const float*)d_in[8];
  const float* a_dst2=(const float*)d_in[9];
  const float* b2    =(const float*)d_in[10];
  const float* Wih0  =(const float*)d_in[11];
  const float* Whh0  =(const float*)d_in[12];
  const float* bih0  =(const float*)d_in[13];
  const float* bhh0  =(const float*)d_in[14];
  const float* Wih1  =(const float*)d_in[15];
  const float* Whh1  =(const float*)d_in[16];
  const float* bih1  =(const float*)d_in[17];
  const float* bhh1  =(const float*)d_in[18];
  const float* Wl    =(const float*)d_in[19];
  const float* bl    =(const float*)d_in[20];

  float* ws   = (float*)d_ws;
  float* agg  = ws;                  // 4194304 [N,128] (dead after k_g12)
  float* s14  = ws + 4194304;        // 131072 [N,4]
  float* gi   = ws;                  // overwrites agg after it's dead
  float* out2 = ws + 8388608;        // 2097152 (k_gat2 output)
  float* h2   = ws + 16777216;       // 2097152
  float* as1  = ws + 18874368;       // 131072
  float* ad1  = as1 + 131072;        // 131072
  float* as2  = ad1 + 131072;        // 32768
  float* ad2  = as2 + 32768;         // 32768
  int* rowptr = (int*)(ad2 + 32768); // 32769 (padded to 32800)
  int* deg    = rowptr + 32800;      // 32768
  int* cur    = deg + 32768;         // 32768 (contiguous with deg: one memset)
  int* col    = cur + 32768;         // 557056
  float* fo   = (float*)d_out;

  hipMemsetAsync(deg, 0, 2*32768*sizeof(int), stream);  // deg + cur

  k_deg   <<<2176,256,0,stream>>>(ei,deg);
  k_scan  <<<1  ,1024,0,stream>>>(deg,rowptr);
  k_fill  <<<2176,256,0,stream>>>(ei,rowptr,cur,col);

  k_alpha1x<<<128 ,256,0,stream>>>(x,W1,a_src1,a_dst1,as1,ad1);
  k_gatx   <<<8192,256,0,stream>>>(rowptr,col,as1,ad1,x,agg,s14);
  k_g12    <<<1024,256,0,stream>>>(agg,W1,s14,b1,W2,a_src2,a_dst2,h2,as2,ad2);
  k_gat2   <<<8192,256,0,stream>>>(rowptr,col,as2,ad2,h2,b2,out2);
  k_gemm_gi<<<512 ,256,0,stream>>>(out2,Wih0,bih0,gi);
  k_gruR   <<<64  ,576,0,stream>>>(gi,Whh0,bhh0,Wih1,bih1,Whh1,bhh1,Wl,bl,fo);
  (void)in_sizes; (void)n_in; (void)out_size; (void)ws_size;
}